// Round 14
// baseline (671.930 us; speedup 1.0000x reference)
//
#include <hip/hip_runtime.h>
#include <math.h>

#define BB   4
#define NPTS 4096
#define NNODE (BB*NPTS)
#define CC   64
#define HHH  4
#define KK   16
#define D1   67
#define SD1  68     // padded row stride for xcat
#define SD2  64

typedef __attribute__((ext_vector_type(2))) float f32x2;

// packed fp32 fma: a.{lo,hi} += u.{lo,hi} * x.{lo,hi}; src0 = SGPR pair
// (candidate row in SGPRs via scalarized uniform loads). IEEE fma per comp.
__device__ __forceinline__ void pkfma_s(f32x2 &a, unsigned long long u, f32x2 x){
    asm("v_pk_fma_f32 %0, %1, %2, %0" : "+v"(a) : "s"(u), "v"(x));
}

// ---------------------------------------------------------------- prep v2 (proven r13)
__global__ __launch_bounds__(256) void k_prep(const float* __restrict__ pf,
                                              const float* __restrict__ pt,
                                              float* __restrict__ xcat,
                                              float* __restrict__ x2)
{
    __shared__ float T[64][69];
    const int tid = threadIdx.x;
    const int nb = blockIdx.x*64;
    const int b = nb>>12;
    const int n0 = nb & (NPTS-1);
    const int l = tid&63, w = tid>>6;
    const float* pfb = pf + (size_t)b*CC*NPTS + n0 + l;
    #pragma unroll
    for (int k=0;k<16;k++){ int c=w*16+k; T[l][c] = pfb[(size_t)c*NPTS]; }
    if (w<3)  T[l][64+w] = pt[(size_t)b*3*NPTS + (size_t)w*NPTS + n0 + l];
    if (w==3) T[l][67] = 0.f;
    __syncthreads();
    if (tid<64){
        float acc=0.f;
        #pragma unroll 1
        for (int c=0;c<67;c++){ float v=T[tid][c]; acc = fmaf(v,v,acc); }
        x2[nb+tid]=acc;
    }
    float* dst = xcat + (size_t)nb*SD1;
    for (int i=tid;i<64*SD1;i+=256) dst[i] = T[i/SD1][i%SD1];
}

// ---------------------------------------------------------------- f64 key pack
// us = monotone uint of fp32 distance; key = us*4096 + local_idx (exact in f64).
// f64 '<' on keys == lex (d, idx), lowest index first == jax.lax.top_k tie-break.
__device__ __forceinline__ double packdi(float dd, int lidx){
    unsigned u = __float_as_uint(dd);
    unsigned us = u ^ ((unsigned)((int)u >> 31) | 0x80000000u);
    return fma((double)us, 4096.0, (double)lidx);
}

// branchless sorted-16 insert: 16-level min/max sift (no divergence)
__device__ __forceinline__ void sift16(double (&dk)[KK], double v){
    #pragma unroll
    for (int j=0;j<KK;j++){
        double lo = fmin(dk[j], v);
        v = fmax(dk[j], v);
        dk[j] = lo;
    }
}

// ---------------------------------------------------------------- fused knn (per segment)
// ONE WAVE per block (64 threads = 64 nodes). The wave scans its segment's
// candidates serially (block-uniform address -> scalar s_load into SGPRs;
// dot = v_pk_fma_f32 with SGPR src0). The wave's sorted register dk[16] IS the
// per-node segment top-16: publish directly. No LDS, no barrier, no merge.
template<int SD, int NS>
__global__ __launch_bounds__(64) void k_knn_seg(const float* __restrict__ X,
    const float* __restrict__ x2, uint2* __restrict__ part)
{
    const int SEGC = NPTS/NS;
    const int l = threadIdx.x;
    const int nodeBase = blockIdx.x*64;      // 64 | 4096 -> never crosses batch
    const int b = nodeBase>>12;
    const int seg = blockIdx.y;
    const int node = nodeBase + l;
    const int nlocal = node & (NPTS-1);

    f32x2 xt[SD/2];
    {
        const f32x2* xr = (const f32x2*)(X + (size_t)node*SD);
        #pragma unroll
        for (int i=0;i<SD/2;i++) xt[i]=xr[i];
    }
    const float x2t = x2[node];

    double dk[KK];
    #pragma unroll
    for (int i=0;i<KK;i++) dk[i]=__builtin_inf();

    const float* Xb  = X  + (size_t)b*NPTS*SD;
    const float* x2b = x2 + (size_t)b*NPTS;

    #pragma unroll 1
    for (int q=0;q<SEGC;q++){
        int lc = seg*SEGC + q;               // block-uniform candidate idx
        const unsigned long long* crow =
            (const unsigned long long*)(Xb + (size_t)lc*SD);   // -> s_load
        float x2c = x2b[lc];
        f32x2 a0 = {0.f,0.f}, a1 = {0.f,0.f};
        #pragma unroll
        for (int i=0;i<SD/4;i++){
            pkfma_s(a0, crow[2*i],   xt[2*i]);
            pkfma_s(a1, crow[2*i+1], xt[2*i+1]);
        }
        float dot = (a0.x + a0.y) + (a1.x + a1.y);
        float dd = fmaf(-2.f, dot, x2t) + x2c;   // (x2_t - 2*dot) + x2_c
        double pd = packdi(dd, lc);
        if (lc==nlocal) pd = __builtin_inf();    // exclude self
        sift16(dk, pd);
    }
    // ---- publish this segment's sorted per-node 16-list (exact key unpack)
    uint2* dst = part + ((size_t)node*NS + seg)*KK;
    #pragma unroll
    for (int i=0;i<KK;i++){
        double bd = dk[i];                       // finite: SEGC-1 >= 16 candidates
        unsigned us = (unsigned)(bd * (1.0/4096.0));       // exact (pow2, trunc)
        unsigned id = (unsigned)(bd - (double)us*4096.0);  // exact residual
        dst[i] = make_uint2(us, id);
    }
}

// ---------------------------------------------------------------- h = X@W, asrc, adst (proven r13)
template<int SD, int D>
__global__ __launch_bounds__(256) void k_gemm_h(const float* __restrict__ X,
    const float* __restrict__ W, const float* __restrict__ a_s,
    const float* __restrict__ a_d,
    float* __restrict__ h, float* __restrict__ asrc, float* __restrict__ adst)
{
    __shared__ float Wl[D*CC];
    __shared__ float asl[CC], adl[CC];
    __shared__ float Xs[16][SD+1];
    const int tid = threadIdx.x;
    for (int i=tid;i<D*CC;i+=256) Wl[i]=W[i];
    if (tid<CC){ asl[tid]=a_s[tid]; adl[tid]=a_d[tid]; }
    const int nodeBase = blockIdx.x*16;
    {
        const float* src = X + (size_t)nodeBase*SD;
        for (int i=tid;i<16*SD;i+=256) Xs[i/SD][i%SD] = src[i];
    }
    __syncthreads();
    const int g = tid>>4, cq = tid&15;
    const int node = nodeBase + g;
    float acc[4]={0,0,0,0};
    const float* xrow = Xs[g];
    #pragma unroll 1
    for (int d=0;d<D;d++){
        float xv = xrow[d];
        const float* wp = Wl + d*CC + cq*4;
        acc[0]=fmaf(xv,wp[0],acc[0]); acc[1]=fmaf(xv,wp[1],acc[1]);
        acc[2]=fmaf(xv,wp[2],acc[2]); acc[3]=fmaf(xv,wp[3],acc[3]);
    }
    ((float4*)(h + (size_t)node*CC))[cq] = make_float4(acc[0],acc[1],acc[2],acc[3]);
    float sp=0.f, dp=0.f;
    #pragma unroll
    for (int j=0;j<4;j++){
        int c = cq*4+j;
        sp = fmaf(acc[j], asl[c], sp);
        dp = fmaf(acc[j], adl[c], dp);
    }
    sp += __shfl_xor(sp,1); sp += __shfl_xor(sp,2);
    dp += __shfl_xor(dp,1); dp += __shfl_xor(dp,2);
    if ((cq&3)==0){
        asrc[(size_t)node*HHH + (cq>>2)] = sp;
        adst[(size_t)node*HHH + (cq>>2)] = dp;
    }
}

// ---------------------------------------------------------------- GAT: fused merge+gather+softmax+PV
// wave per node; NS*16 (us,idx) keys -> u64, NS*16/64 per lane; 16 rounds of
// butterfly-min == ascending lex (d,idx) == k-way merge of sorted lists.
template<int NS>
__global__ __launch_bounds__(256) void k_gat(const float* __restrict__ h,
    const float* __restrict__ asrc, const float* __restrict__ adst,
    const uint2* __restrict__ part, const float* __restrict__ bias,
    float* __restrict__ f, float* __restrict__ x2out)
{
    const int E = NS*KK/64;                    // keys per lane
    int wid = threadIdx.x>>6, lane = threadIdx.x&63;
    int node = blockIdx.x*4 + wid;
    int bbase = (node>>12)<<12;
    int hh = lane>>4;
    const uint2* pn = part + (size_t)node*(NS*KK);
    unsigned long long ek[E];
    #pragma unroll
    for (int i=0;i<E;i++){
        uint2 v = pn[i*64 + lane];
        ek[i] = ((unsigned long long)v.x<<16) | (unsigned long long)v.y;
    }
    float ad = adst[(size_t)node*HHH+hh];
    int js[KK]; float e[KK];
    #pragma unroll 1
    for (int r=0;r<KK;r++){
        unsigned long long m = ek[0];
        #pragma unroll
        for (int i=1;i<E;i++) if (ek[i]<m) m=ek[i];
        #pragma unroll
        for (int s=32;s>0;s>>=1){
            unsigned long long o = __shfl_xor(m, s);
            if (o<m) m=o;
        }
        js[r] = bbase + (int)(m & 0xFFFFull);
        #pragma unroll
        for (int i=0;i<E;i++) if (ek[i]==m) ek[i] = ~0ull;  // keys unique
    }
    #pragma unroll
    for (int k=0;k<KK;k++){
        int j = js[k] & (NNODE-1);             // safety clamp
        js[k]=j;
        float ev = asrc[(size_t)j*HHH+hh] + ad;
        e[k] = ev>0.f ? ev : 0.2f*ev;          // leaky_relu 0.2
    }
    float m = e[0];
    #pragma unroll
    for (int k=1;k<KK;k++) m = fmaxf(m,e[k]);
    float s=0.f;
    #pragma unroll
    for (int k=0;k<KK;k++){ e[k]=__expf(e[k]-m); s+=e[k]; }
    float inv = 1.f/s;
    float acc=0.f;
    #pragma unroll
    for (int k=0;k<KK;k++)
        acc = fmaf(e[k]*inv, h[(size_t)js[k]*CC + lane], acc);
    float val = acc + bias[lane];
    val = val>0.f ? val : expm1f(val);          // elu
    f[(size_t)node*CC+lane]=val;
    float sq = val*val;
    #pragma unroll
    for (int s2=32;s2>0;s2>>=1) sq += __shfl_xor(sq, s2);
    if (lane==0) x2out[node]=sq;
}

// ---------------------------------------------------------------- final MLP + transpose-out (proven r13)
__global__ __launch_bounds__(256) void k_final(const float* __restrict__ f1,
    const float* __restrict__ f2, const float* __restrict__ Wm,
    const float* __restrict__ bm, float* __restrict__ out)
{
    __shared__ float Wl[2*CC*CC];
    __shared__ float Xs[16][2*CC+1];
    const int tid=threadIdx.x;
    for (int i=tid;i<2*CC*CC;i+=256) Wl[i]=Wm[i];
    const int nodeBase = blockIdx.x*16;
    {
        const float* s1 = f1 + (size_t)nodeBase*CC;
        for (int i=tid;i<16*CC;i+=256) Xs[i/CC][i%CC] = s1[i];
        const float* s2 = f2 + (size_t)nodeBase*CC;
        for (int i=tid;i<16*CC;i+=256) Xs[i/CC][CC + i%CC] = s2[i];
    }
    __syncthreads();
    const int g = tid>>4, cq = tid&15;
    const int node = nodeBase + g;
    const int b = node>>12, n = node&(NPTS-1);
    float acc[4]={0,0,0,0};
    const float* xrow = Xs[g];
    #pragma unroll 1
    for (int d=0;d<2*CC;d++){
        float xv = xrow[d];
        const float* wp = Wl + d*CC + cq*4;
        acc[0]=fmaf(xv,wp[0],acc[0]); acc[1]=fmaf(xv,wp[1],acc[1]);
        acc[2]=fmaf(xv,wp[2],acc[2]); acc[3]=fmaf(xv,wp[3],acc[3]);
    }
    #pragma unroll
    for (int j=0;j<4;j++){
        int c = cq*4+j;
        float v = acc[j] + bm[c];
        v = v>0.f ? v : expm1f(v);
        out[(size_t)b*CC*NPTS + (size_t)c*NPTS + n] = v;
    }
}

// ---------------------------------------------------------------- ws-too-small fallback
__global__ void k_zero(float* out, int n){
    int i = blockIdx.x*256 + threadIdx.x;
    if (i<n) out[i] = 0.f;
}

// ---------------------------------------------------------------- launcher
extern "C" void kernel_launch(void* const* d_in, const int* in_sizes, int n_in,
                              void* d_out, int out_size, void* d_ws, size_t ws_size,
                              hipStream_t stream) {
    const float* pf  = (const float*)d_in[0];
    const float* pt  = (const float*)d_in[1];
    const float* W1  = (const float*)d_in[2];
    const float* a1s = (const float*)d_in[3];
    const float* a1d = (const float*)d_in[4];
    const float* b1  = (const float*)d_in[5];
    const float* W2  = (const float*)d_in[6];
    const float* a2s = (const float*)d_in[7];
    const float* a2d = (const float*)d_in[8];
    const float* b2  = (const float*)d_in[9];
    const float* Wm  = (const float*)d_in[10];
    const float* bm  = (const float*)d_in[11];
    float* out = (float*)d_out;

    // ---- workspace layout (floats), ~14.5 MB + partials
    float* ws = (float*)d_ws;
    float* xcat  = ws;                             // 16384*68
    float* f2    = xcat;                           // alias (xcat dead after gemm1)
    float* h     = xcat + (size_t)NNODE*SD1;       // 16384*64
    float* f1    = h    + (size_t)NNODE*CC;        // 16384*64
    float* x2    = f1   + (size_t)NNODE*CC;        // 16384
    float* asrc  = x2   + NNODE;                   // 16384*4
    float* adst  = asrc + (size_t)NNODE*HHH;       // 16384*4
    float* wsend = adst + (size_t)NNODE*HHH;
    uint2* part  = (uint2*)wsend;
    size_t base_bytes = (size_t)(wsend - ws)*sizeof(float);
    size_t need16 = base_bytes + (size_t)NNODE*16*KK*sizeof(uint2) + 64;  // +32 MB
    size_t need8  = base_bytes + (size_t)NNODE*8*KK*sizeof(uint2) + 64;   // +16 MB

    if (ws_size < need8) {   // diagnostic fallback: clean numeric fail, not a crash
        k_zero<<<(out_size+255)/256, 256, 0, stream>>>(out, out_size);
        return;
    }

    k_prep<<<NNODE/64, 256, 0, stream>>>(pf, pt, xcat, x2);

    if (ws_size >= need16) {
        dim3 g(NNODE/64, 16);   // 4096 one-wave blocks -> 16 waves/CU
        k_knn_seg<SD1,16><<<g, 64, 0, stream>>>(xcat, x2, part);
        k_gemm_h<SD1, D1><<<NNODE/16, 256, 0, stream>>>(xcat, W1, a1s, a1d, h, asrc, adst);
        k_gat<16><<<NNODE/4, 256, 0, stream>>>(h, asrc, adst, part, b1, f1, x2);
        k_knn_seg<SD2,16><<<g, 64, 0, stream>>>(f1, x2, part);
        k_gemm_h<SD2, CC><<<NNODE/16, 256, 0, stream>>>(f1, W2, a2s, a2d, h, asrc, adst);
        k_gat<16><<<NNODE/4, 256, 0, stream>>>(h, asrc, adst, part, b2, f2, x2);
    } else {
        dim3 g(NNODE/64, 8);    // 2048 one-wave blocks
        k_knn_seg<SD1,8><<<g, 64, 0, stream>>>(xcat, x2, part);
        k_gemm_h<SD1, D1><<<NNODE/16, 256, 0, stream>>>(xcat, W1, a1s, a1d, h, asrc, adst);
        k_gat<8><<<NNODE/4, 256, 0, stream>>>(h, asrc, adst, part, b1, f1, x2);
        k_knn_seg<SD2,8><<<g, 64, 0, stream>>>(f1, x2, part);
        k_gemm_h<SD2, CC><<<NNODE/16, 256, 0, stream>>>(f1, W2, a2s, a2d, h, asrc, adst);
        k_gat<8><<<NNODE/4, 256, 0, stream>>>(h, asrc, adst, part, b2, f2, x2);
    }

    k_final<<<NNODE/16, 256, 0, stream>>>(f1, f2, Wm, bm, out);
}

// Round 15
// 620.632 us; speedup vs baseline: 1.0827x; 1.0827x over previous
//
#include <hip/hip_runtime.h>
#include <math.h>

#define BB   4
#define NPTS 4096
#define NNODE (BB*NPTS)
#define CC   64
#define HHH  4
#define KK   16
#define D1   67
#define SD1  68     // padded row stride for xcat
#define SD2  64
#define NSTR 4      // candidate streams (= waves) per knn block
#define USTR (NSTR*KK + 2)   // per-node LDS merge stride (66 entries)

typedef __attribute__((ext_vector_type(2))) float f32x2;

// packed fp32 fma: a.{lo,hi} += u.{lo,hi} * x.{lo,hi}; src0 = SGPR pair
// (candidate row in SGPRs via scalarized uniform loads). IEEE fma per comp.
__device__ __forceinline__ void pkfma_s(f32x2 &a, unsigned long long u, f32x2 x){
    asm("v_pk_fma_f32 %0, %1, %2, %0" : "+v"(a) : "s"(u), "v"(x));
}

// ---------------------------------------------------------------- prep v2 (proven r13)
__global__ __launch_bounds__(256) void k_prep(const float* __restrict__ pf,
                                              const float* __restrict__ pt,
                                              float* __restrict__ xcat,
                                              float* __restrict__ x2)
{
    __shared__ float T[64][69];
    const int tid = threadIdx.x;
    const int nb = blockIdx.x*64;
    const int b = nb>>12;
    const int n0 = nb & (NPTS-1);
    const int l = tid&63, w = tid>>6;
    const float* pfb = pf + (size_t)b*CC*NPTS + n0 + l;
    #pragma unroll
    for (int k=0;k<16;k++){ int c=w*16+k; T[l][c] = pfb[(size_t)c*NPTS]; }
    if (w<3)  T[l][64+w] = pt[(size_t)b*3*NPTS + (size_t)w*NPTS + n0 + l];
    if (w==3) T[l][67] = 0.f;
    __syncthreads();
    if (tid<64){
        float acc=0.f;
        #pragma unroll 1
        for (int c=0;c<67;c++){ float v=T[tid][c]; acc = fmaf(v,v,acc); }
        x2[nb+tid]=acc;
    }
    float* dst = xcat + (size_t)nb*SD1;
    for (int i=tid;i<64*SD1;i+=256) dst[i] = T[i/SD1][i%SD1];
}

// ---------------------------------------------------------------- f64 key pack
// us = monotone uint of fp32 distance; key = us*4096 + local_idx (exact in f64).
// f64 '<' on keys == lex (d, idx), lowest index first == jax.lax.top_k tie-break.
__device__ __forceinline__ double packdi(float dd, int lidx){
    unsigned u = __float_as_uint(dd);
    unsigned us = u ^ ((unsigned)((int)u >> 31) | 0x80000000u);
    return fma((double)us, 4096.0, (double)lidx);
}

// branchless sorted-16 insert: 16-level min/max sift (no divergence)
__device__ __forceinline__ void sift16(double (&dk)[KK], double v){
    #pragma unroll
    for (int j=0;j<KK;j++){
        double lo = fmin(dk[j], v);
        v = fmax(dk[j], v);
        dk[j] = lo;
    }
}

// ---------------------------------------------------------------- fused knn (per segment)
// PROVEN r13 structure: block = 256 thr = 4 waves, 64 nodes; wave w scans
// c ≡ w (mod 4) ascending; rows wave-uniform -> s_load into SGPRs; dot =
// v_pk_fma_f32 (SGPR src0), bit-identical to the 4-chain scalar sum. Per-lane
// sorted top-16 f64 keys -> (u32,u16) LDS -> block 4-way merge -> global.
template<int SD, int NS>
__global__ __launch_bounds__(256) void k_knn_seg(const float* __restrict__ X,
    const float* __restrict__ x2, uint2* __restrict__ part)
{
    __shared__ unsigned       mus[64*USTR];
    __shared__ unsigned short mix[64*USTR];

    const int SEGC = NPTS/NS;
    const int tid = threadIdx.x;
    const int w = __builtin_amdgcn_readfirstlane(tid>>6);
    const int l = tid&63;
    const int b = blockIdx.y, seg = blockIdx.z;
    const int nodeBase = b*NPTS + blockIdx.x*64;
    const int node = nodeBase + l;
    const int nlocal = blockIdx.x*64 + l;

    f32x2 xt[SD/2];
    {
        const f32x2* xr = (const f32x2*)(X + (size_t)node*SD);
        #pragma unroll
        for (int i=0;i<SD/2;i++) xt[i]=xr[i];
    }
    const float x2t = x2[node];

    double dk[KK];
    #pragma unroll
    for (int i=0;i<KK;i++) dk[i]=__builtin_inf();

    const float* Xb  = X  + (size_t)b*NPTS*SD;
    const float* x2b = x2 + (size_t)b*NPTS;

    #pragma unroll 1
    for (int q=0;q<SEGC/NSTR;q++){
        int lc = seg*SEGC + q*NSTR + w;
        const unsigned long long* crow =
            (const unsigned long long*)(Xb + (size_t)lc*SD);   // uniform -> s_load
        float x2c = x2b[lc];
        f32x2 a0 = {0.f,0.f}, a1 = {0.f,0.f};
        #pragma unroll
        for (int i=0;i<SD/4;i++){
            pkfma_s(a0, crow[2*i],   xt[2*i]);
            pkfma_s(a1, crow[2*i+1], xt[2*i+1]);
        }
        float dot = (a0.x + a0.y) + (a1.x + a1.y);
        float dd = fmaf(-2.f, dot, x2t) + x2c;   // (x2_t - 2*dot) + x2_c
        double pd = packdi(dd, lc);
        if (lc==nlocal) pd = __builtin_inf();
        sift16(dk, pd);
    }
    #pragma unroll
    for (int i=0;i<KK;i++){
        double bd = dk[i];
        unsigned us = (unsigned)(bd * (1.0/4096.0));       // exact (pow2, trunc)
        unsigned id = (unsigned)(bd - (double)us*4096.0);  // exact residual
        mus[l*USTR + w*KK + i] = us;
        mix[l*USTR + w*KK + i] = (unsigned short)id;
    }
    __syncthreads();
    if (tid < 64){
        const unsigned*       mu = mus + tid*USTR;
        const unsigned short* mi = mix + tid*USTR;
        unsigned hu[NSTR], hx[NSTR]; int pp[NSTR];
        #pragma unroll
        for (int s=0;s<NSTR;s++){ pp[s]=0; hu[s]=mu[s*KK]; hx[s]=mi[s*KK]; }
        size_t obase = ((size_t)(nodeBase + tid)*NS + seg)*KK;
        #pragma unroll 1
        for (int r=0;r<KK;r++){
            unsigned bu=hu[0], bx=hx[0]; int bw=0;
            #pragma unroll
            for (int s=1;s<NSTR;s++){
                if (hu[s]<bu || (hu[s]==bu && hx[s]<bx)){ bu=hu[s]; bx=hx[s]; bw=s; }
            }
            part[obase + r] = make_uint2(bu, bx);
            #pragma unroll
            for (int s=0;s<NSTR;s++){
                if (bw==s){
                    int np = ++pp[s];
                    bool ok = np < KK;
                    unsigned nu = mu[s*KK + np];
                    unsigned nx = mi[s*KK + np];
                    hu[s] = ok ? nu : 0xFFFFFFFFu;
                    hx[s] = ok ? nx : 0xFFFFu;
                }
            }
        }
    }
}

// ---------------------------------------------------------------- h = X@W, asrc, adst (proven r13)
template<int SD, int D>
__global__ __launch_bounds__(256) void k_gemm_h(const float* __restrict__ X,
    const float* __restrict__ W, const float* __restrict__ a_s,
    const float* __restrict__ a_d,
    float* __restrict__ h, float* __restrict__ asrc, float* __restrict__ adst)
{
    __shared__ float Wl[D*CC];
    __shared__ float asl[CC], adl[CC];
    __shared__ float Xs[16][SD+1];
    const int tid = threadIdx.x;
    for (int i=tid;i<D*CC;i+=256) Wl[i]=W[i];
    if (tid<CC){ asl[tid]=a_s[tid]; adl[tid]=a_d[tid]; }
    const int nodeBase = blockIdx.x*16;
    {
        const float* src = X + (size_t)nodeBase*SD;
        for (int i=tid;i<16*SD;i+=256) Xs[i/SD][i%SD] = src[i];
    }
    __syncthreads();
    const int g = tid>>4, cq = tid&15;
    const int node = nodeBase + g;
    float acc[4]={0,0,0,0};
    const float* xrow = Xs[g];
    #pragma unroll 1
    for (int d=0;d<D;d++){
        float xv = xrow[d];
        const float* wp = Wl + d*CC + cq*4;
        acc[0]=fmaf(xv,wp[0],acc[0]); acc[1]=fmaf(xv,wp[1],acc[1]);
        acc[2]=fmaf(xv,wp[2],acc[2]); acc[3]=fmaf(xv,wp[3],acc[3]);
    }
    ((float4*)(h + (size_t)node*CC))[cq] = make_float4(acc[0],acc[1],acc[2],acc[3]);
    float sp=0.f, dp=0.f;
    #pragma unroll
    for (int j=0;j<4;j++){
        int c = cq*4+j;
        sp = fmaf(acc[j], asl[c], sp);
        dp = fmaf(acc[j], adl[c], dp);
    }
    sp += __shfl_xor(sp,1); sp += __shfl_xor(sp,2);
    dp += __shfl_xor(dp,1); dp += __shfl_xor(dp,2);
    if ((cq&3)==0){
        asrc[(size_t)node*HHH + (cq>>2)] = sp;
        adst[(size_t)node*HHH + (cq>>2)] = dp;
    }
}

// ---------------------------------------------------------------- GAT: fused merge+gather+softmax+PV
// wave per node; NS*16 (us,idx) keys -> u64, NS*16/64 per lane; 16 rounds of
// butterfly-min == ascending lex (d,idx) == k-way merge of sorted lists.
template<int NS>
__global__ __launch_bounds__(256) void k_gat(const float* __restrict__ h,
    const float* __restrict__ asrc, const float* __restrict__ adst,
    const uint2* __restrict__ part, const float* __restrict__ bias,
    float* __restrict__ f, float* __restrict__ x2out)
{
    const int E = NS*KK/64;                    // keys per lane
    int wid = threadIdx.x>>6, lane = threadIdx.x&63;
    int node = blockIdx.x*4 + wid;
    int bbase = (node>>12)<<12;
    int hh = lane>>4;
    const uint2* pn = part + (size_t)node*(NS*KK);
    unsigned long long ek[E];
    #pragma unroll
    for (int i=0;i<E;i++){
        uint2 v = pn[i*64 + lane];
        ek[i] = ((unsigned long long)v.x<<16) | (unsigned long long)v.y;
    }
    float ad = adst[(size_t)node*HHH+hh];
    int js[KK]; float e[KK];
    #pragma unroll 1
    for (int r=0;r<KK;r++){
        unsigned long long m = ek[0];
        #pragma unroll
        for (int i=1;i<E;i++) if (ek[i]<m) m=ek[i];
        #pragma unroll
        for (int s=32;s>0;s>>=1){
            unsigned long long o = __shfl_xor(m, s);
            if (o<m) m=o;
        }
        js[r] = bbase + (int)(m & 0xFFFFull);
        #pragma unroll
        for (int i=0;i<E;i++) if (ek[i]==m) ek[i] = ~0ull;  // keys unique
    }
    #pragma unroll
    for (int k=0;k<KK;k++){
        int j = js[k] & (NNODE-1);             // safety clamp
        js[k]=j;
        float ev = asrc[(size_t)j*HHH+hh] + ad;
        e[k] = ev>0.f ? ev : 0.2f*ev;          // leaky_relu 0.2
    }
    float m = e[0];
    #pragma unroll
    for (int k=1;k<KK;k++) m = fmaxf(m,e[k]);
    float s=0.f;
    #pragma unroll
    for (int k=0;k<KK;k++){ e[k]=__expf(e[k]-m); s+=e[k]; }
    float inv = 1.f/s;
    float acc=0.f;
    #pragma unroll
    for (int k=0;k<KK;k++)
        acc = fmaf(e[k]*inv, h[(size_t)js[k]*CC + lane], acc);
    float val = acc + bias[lane];
    val = val>0.f ? val : expm1f(val);          // elu
    f[(size_t)node*CC+lane]=val;
    float sq = val*val;
    #pragma unroll
    for (int s2=32;s2>0;s2>>=1) sq += __shfl_xor(sq, s2);
    if (lane==0) x2out[node]=sq;
}

// ---------------------------------------------------------------- final MLP + transpose-out (proven r13)
__global__ __launch_bounds__(256) void k_final(const float* __restrict__ f1,
    const float* __restrict__ f2, const float* __restrict__ Wm,
    const float* __restrict__ bm, float* __restrict__ out)
{
    __shared__ float Wl[2*CC*CC];
    __shared__ float Xs[16][2*CC+1];
    const int tid=threadIdx.x;
    for (int i=tid;i<2*CC*CC;i+=256) Wl[i]=Wm[i];
    const int nodeBase = blockIdx.x*16;
    {
        const float* s1 = f1 + (size_t)nodeBase*CC;
        for (int i=tid;i<16*CC;i+=256) Xs[i/CC][i%CC] = s1[i];
        const float* s2 = f2 + (size_t)nodeBase*CC;
        for (int i=tid;i<16*CC;i+=256) Xs[i/CC][CC + i%CC] = s2[i];
    }
    __syncthreads();
    const int g = tid>>4, cq = tid&15;
    const int node = nodeBase + g;
    const int b = node>>12, n = node&(NPTS-1);
    float acc[4]={0,0,0,0};
    const float* xrow = Xs[g];
    #pragma unroll 1
    for (int d=0;d<2*CC;d++){
        float xv = xrow[d];
        const float* wp = Wl + d*CC + cq*4;
        acc[0]=fmaf(xv,wp[0],acc[0]); acc[1]=fmaf(xv,wp[1],acc[1]);
        acc[2]=fmaf(xv,wp[2],acc[2]); acc[3]=fmaf(xv,wp[3],acc[3]);
    }
    #pragma unroll
    for (int j=0;j<4;j++){
        int c = cq*4+j;
        float v = acc[j] + bm[c];
        v = v>0.f ? v : expm1f(v);
        out[(size_t)b*CC*NPTS + (size_t)c*NPTS + n] = v;
    }
}

// ---------------------------------------------------------------- ws-too-small fallback
__global__ void k_zero(float* out, int n){
    int i = blockIdx.x*256 + threadIdx.x;
    if (i<n) out[i] = 0.f;
}

// ---------------------------------------------------------------- launcher
extern "C" void kernel_launch(void* const* d_in, const int* in_sizes, int n_in,
                              void* d_out, int out_size, void* d_ws, size_t ws_size,
                              hipStream_t stream) {
    const float* pf  = (const float*)d_in[0];
    const float* pt  = (const float*)d_in[1];
    const float* W1  = (const float*)d_in[2];
    const float* a1s = (const float*)d_in[3];
    const float* a1d = (const float*)d_in[4];
    const float* b1  = (const float*)d_in[5];
    const float* W2  = (const float*)d_in[6];
    const float* a2s = (const float*)d_in[7];
    const float* a2d = (const float*)d_in[8];
    const float* b2  = (const float*)d_in[9];
    const float* Wm  = (const float*)d_in[10];
    const float* bm  = (const float*)d_in[11];
    float* out = (float*)d_out;

    // ---- workspace layout (floats), ~14.5 MB + partials
    float* ws = (float*)d_ws;
    float* xcat  = ws;                             // 16384*68
    float* f2    = xcat;                           // alias (xcat dead after gemm1)
    float* h     = xcat + (size_t)NNODE*SD1;       // 16384*64
    float* f1    = h    + (size_t)NNODE*CC;        // 16384*64
    float* x2    = f1   + (size_t)NNODE*CC;        // 16384
    float* asrc  = x2   + NNODE;                   // 16384*4
    float* adst  = asrc + (size_t)NNODE*HHH;       // 16384*4
    float* wsend = adst + (size_t)NNODE*HHH;
    uint2* part  = (uint2*)wsend;
    size_t base_bytes = (size_t)(wsend - ws)*sizeof(float);
    size_t need16 = base_bytes + (size_t)NNODE*16*KK*sizeof(uint2) + 64;  // +32 MB
    size_t need8  = base_bytes + (size_t)NNODE*8*KK*sizeof(uint2) + 64;   // +16 MB

    if (ws_size < need8) {   // diagnostic fallback: clean numeric fail, not a crash
        k_zero<<<(out_size+255)/256, 256, 0, stream>>>(out, out_size);
        return;
    }

    k_prep<<<NNODE/64, 256, 0, stream>>>(pf, pt, xcat, x2);

    if (ws_size >= need16) {
        dim3 g(NPTS/64, BB, 16);   // 4096 four-wave blocks, SEGC=256
        k_knn_seg<SD1,16><<<g, 256, 0, stream>>>(xcat, x2, part);
        k_gemm_h<SD1, D1><<<NNODE/16, 256, 0, stream>>>(xcat, W1, a1s, a1d, h, asrc, adst);
        k_gat<16><<<NNODE/4, 256, 0, stream>>>(h, asrc, adst, part, b1, f1, x2);
        k_knn_seg<SD2,16><<<g, 256, 0, stream>>>(f1, x2, part);
        k_gemm_h<SD2, CC><<<NNODE/16, 256, 0, stream>>>(f1, W2, a2s, a2d, h, asrc, adst);
        k_gat<16><<<NNODE/4, 256, 0, stream>>>(h, asrc, adst, part, b2, f2, x2);
    } else {
        dim3 g(NPTS/64, BB, 8);    // proven r13 path
        k_knn_seg<SD1,8><<<g, 256, 0, stream>>>(xcat, x2, part);
        k_gemm_h<SD1, D1><<<NNODE/16, 256, 0, stream>>>(xcat, W1, a1s, a1d, h, asrc, adst);
        k_gat<8><<<NNODE/4, 256, 0, stream>>>(h, asrc, adst, part, b1, f1, x2);
        k_knn_seg<SD2,8><<<g, 256, 0, stream>>>(f1, x2, part);
        k_gemm_h<SD2, CC><<<NNODE/16, 256, 0, stream>>>(f1, W2, a2s, a2d, h, asrc, adst);
        k_gat<8><<<NNODE/4, 256, 0, stream>>>(h, asrc, adst, part, b2, f2, x2);
    }

    k_final<<<NNODE/16, 256, 0, stream>>>(f1, f2, Wm, bm, out);
}